// Round 11
// baseline (18852.336 us; speedup 1.0000x reference)
//
#include <hip/hip_runtime.h>
#include <hip/hip_bf16.h>
#include <hip/hip_cooperative_groups.h>

namespace cg = cooperative_groups;

typedef __attribute__((ext_vector_type(4))) int   i32x4;
typedef __attribute__((ext_vector_type(4))) float f32x4;
typedef __attribute__((ext_vector_type(4))) short s16x4;
typedef __attribute__((ext_vector_type(8))) short s16x8;

#define B_  32
#define T_  512
#define F_  128
#define H_  2048
#define V_  32

static __device__ __forceinline__ int clampi16(int v) {
  v = v < -32768 ? -32768 : v;
  return v > 32767 ? 32767 : v;
}
static __device__ __forceinline__ short f2bf(float f) {
  union { __hip_bfloat16 b; short s; } u; u.b = __float2bfloat16(f); return u.s;
}

// XLA-CPU tanh under legacy fast-math: Eigen/XLA rational approximation with
// FMA-contracted Horner chains. (R10-validated bit-level grading target.)
static __device__ __forceinline__ float xla_tanh_fma(float x) {
#pragma clang fp contract(off)
  const float kClamp = 7.90531110763549805f;
  float xc = fminf(fmaxf(x, -kClamp), kClamp);
  float x2 = xc * xc;
  float a;
  a = -2.76076847742355e-16f;                          // alpha_13
  a = __builtin_fmaf(a, x2, 2.00018790482477e-13f);    // alpha_11
  a = __builtin_fmaf(a, x2, -8.60467152213735e-11f);   // alpha_9
  a = __builtin_fmaf(a, x2, 5.12229709037114e-08f);    // alpha_7
  a = __builtin_fmaf(a, x2, 1.48572235717979e-05f);    // alpha_5
  a = __builtin_fmaf(a, x2, 6.37261928875436e-04f);    // alpha_3
  a = __builtin_fmaf(a, x2, 4.89352455891786e-03f);    // alpha_1
  float num = xc * a;
  float b;
  b = 1.19825839466702e-06f;                           // beta_6
  b = __builtin_fmaf(b, x2, 1.18534705686654e-04f);    // beta_4
  b = __builtin_fmaf(b, x2, 2.26843463243900e-03f);    // beta_2
  b = __builtin_fmaf(b, x2, 4.89352518554385e-03f);    // beta_0
  float r = num / b;                                   // IEEE div
  return (fabsf(x) < 0.0004f) ? x : r;
}

// ---------------- Phase 0: pack weights to bf16 (exact: |w|<=7) ----------------
__global__ __launch_bounds__(256) void pack_k(const int* __restrict__ Wr4,
                                              const int* __restrict__ Wi4,
                                              const float* __restrict__ Wo,
                                              short* __restrict__ WrB,
                                              short* __restrict__ WiB,
                                              short* __restrict__ WoB) {
  const int idx = blockIdx.x * 256 + threadIdx.x;  // grid 4096 -> 1,048,576
  {
    i32x4 v = *(const i32x4*)(Wr4 + (size_t)idx * 4);
    s16x4 o;
#pragma unroll
    for (int r = 0; r < 4; ++r) o[r] = f2bf((float)v[r]);
    *(s16x4*)(WrB + (size_t)idx * 4) = o;
  }
  if (idx < (H_ * F_ / 4)) {
    i32x4 v = *(const i32x4*)(Wi4 + (size_t)idx * 4);
    s16x4 o;
#pragma unroll
    for (int r = 0; r < 4; ++r) o[r] = f2bf((float)v[r]);
    *(s16x4*)(WiB + (size_t)idx * 4) = o;
  }
  if (idx < (V_ * H_ / 4)) {
    f32x4 f = *(const f32x4*)(Wo + (size_t)idx * 4);
    s16x4 o;
#pragma unroll
    for (int r = 0; r < 4; ++r) o[r] = f2bf(f[r]);
    *(s16x4*)(WoB + (size_t)idx * 4) = o;
  }
}

// ---------------- Phase 1: Oin[t][j][b] = clip(u_int @ Wi^T, int16) ----------------
__global__ __launch_bounds__(256) void in_gemm(const float* __restrict__ x,
                                               const short* __restrict__ WiB,
                                               short* __restrict__ Oin) {
  const int t  = blockIdx.x;
  const int jt = blockIdx.y;
  const int tid = threadIdx.x;
  const int l = tid & 63, w = tid >> 6;
  const int mh = w & 1, q = w >> 1;
  const int lr = l & 15, lc = l >> 4;
  const int brow = mh * 16 + lr;

  s16x8 af[4];
  const float* xp = x + ((size_t)brow * T_ + t) * F_;
#pragma unroll
  for (int kk = 0; kk < 4; ++kk) {
    f32x4 f0 = *(const f32x4*)(xp + kk * 32 + lc * 8);
    f32x4 f1 = *(const f32x4*)(xp + kk * 32 + lc * 8 + 4);
    s16x8 a;
#pragma unroll
    for (int c = 0; c < 4; ++c) a[c]     = f2bf(rintf(f0[c] * 7.0f));
#pragma unroll
    for (int c = 0; c < 4; ++c) a[4 + c] = f2bf(rintf(f1[c] * 7.0f));
    af[kk] = a;
  }
#pragma unroll
  for (int s = 0; s < 4; ++s) {
    const int j = jt * 128 + q * 64 + s * 16 + lr;
    f32x4 acc = {0.f, 0.f, 0.f, 0.f};
#pragma unroll
    for (int kk = 0; kk < 4; ++kk) {
      s16x8 b = *(const s16x8*)(WiB + (size_t)j * F_ + kk * 32 + lc * 8);
      acc = __builtin_amdgcn_mfma_f32_16x16x32_bf16(af[kk], b, acc, 0, 0, 0);
    }
    short* op = Oin + ((size_t)t * H_ + j) * B_ + mh * 16 + lc * 4;
    s16x4 ov;
#pragma unroll
    for (int r = 0; r < 4; ++r) ov[r] = (short)clampi16((int)acc[r]);
    *(s16x4*)op = ov;
  }
}

// ---------------- Phase 2: full recurrence, ONE cooperative launch ----------------
// 64 blocks x 256 thr (1 wave/SIMD). Wr fragments live in 256 VGPRs/lane for
// all 512 steps (zero W traffic in the loop). grid.sync() between steps.
// Numerics bit-identical to the R10-validated step_k.
__global__ __launch_bounds__(256, 1) void recur_coop(const short* __restrict__ WrB,
                                                     const short* __restrict__ Oin,
                                                     const float* __restrict__ Sres,
                                                     const float* __restrict__ Sin,
                                                     short* __restrict__ Hb,
                                                     short* __restrict__ Hs) {
#pragma clang fp contract(off)
  cg::grid_group grid = cg::this_grid();
  const int tid = threadIdx.x;
  const int l = tid & 63, w = tid >> 6;
  const int mh = w & 1, nh = w >> 1;
  const int lr = l & 15, lc = l >> 4;
  const int jl = blockIdx.x * 32 + nh * 16 + lr;   // unit (MFMA col)
  const int b0 = mh * 16;

  const float RC49 = 1.0f / 49.0f;
  const float sres = Sres[jl] * RC49;    // fast-math: x/49 -> x*(1/49)
  const float sinl = Sin[jl]  * RC49;

  // Preload W row fragments: 64 x s16x8 = 256 VGPRs (loop-invariant).
  const short* wrow = WrB + (size_t)jl * H_ + lc * 8;
  s16x8 wreg[64];
#pragma unroll
  for (int kk = 0; kk < 64; ++kk) wreg[kk] = *(const s16x8*)(wrow + kk * 32);

  for (int t = 0; t < T_; ++t) {
    const short* hin  = Hb + (t & 1) * (B_ * H_);
    short*       hout = Hb + ((t + 1) & 1) * (B_ * H_);
    const short* hrow = hin + (size_t)(b0 + lr) * H_ + lc * 8;

    f32x4 acc0 = {0.f, 0.f, 0.f, 0.f}, acc1 = {0.f, 0.f, 0.f, 0.f};
#pragma unroll 8
    for (int kk = 0; kk < 64; kk += 2) {
      s16x8 a0 = *(const s16x8*)(hrow + kk * 32);
      s16x8 a1 = *(const s16x8*)(hrow + kk * 32 + 32);
      acc0 = __builtin_amdgcn_mfma_f32_16x16x32_bf16(a0, wreg[kk],     acc0, 0, 0, 0);
      acc1 = __builtin_amdgcn_mfma_f32_16x16x32_bf16(a1, wreg[kk + 1], acc1, 0, 0, 0);
    }

    const s16x4 oin = *(const s16x4*)(Oin + ((size_t)t * H_ + jl) * B_ + b0 + lc * 4);

#pragma unroll
    for (int r = 0; r < 4; ++r) {
      const int b = b0 + lc * 4 + r;
      const float resf = acc0[r] + acc1[r];          // exact integer in f32
      const int   res  = clampi16((int)resf);
      const float t2   = (float)oin[r] * sinl;
      const float z    = __builtin_fmaf((float)res, sres, t2);
      const float h    = xla_tanh_fma(z);
      const float hc   = fminf(fmaxf(h, -1.0f), 1.0f);
      Hs[((size_t)b * T_ + t) * H_ + jl] = f2bf(h);
      hout[(size_t)b * H_ + jl] = f2bf(rintf(hc * 7.0f));
    }

    if (t != T_ - 1) {
      __threadfence();
      grid.sync();
    }
  }
}

// ---------------- Phase 3: out(f32) = Hs(bf16) @ Wo(bf16)^T + bias ----------------
__global__ __launch_bounds__(256) void out_gemm(const unsigned short* __restrict__ Hs,
                                                const unsigned short* __restrict__ WoB,
                                                const float* __restrict__ bias,
                                                float* __restrict__ out) {
  const int tid = threadIdx.x;
  const int l = tid & 63, w = tid >> 6;
  const int m0 = blockIdx.x * 64 + w * 16;
  const int lr = l & 15, lc = l >> 4;

  f32x4 acc0 = {0.f, 0.f, 0.f, 0.f}, acc1 = {0.f, 0.f, 0.f, 0.f};
  const unsigned short* arow = Hs  + (size_t)(m0 + lr) * H_ + lc * 8;
  const unsigned short* bp0  = WoB + (size_t)lr * H_        + lc * 8;
  const unsigned short* bp1  = WoB + (size_t)(16 + lr) * H_ + lc * 8;
#pragma unroll 8
  for (int kk = 0; kk < 64; ++kk) {
    s16x8 a  = *(const s16x8*)(arow + kk * 32);
    s16x8 b0 = *(const s16x8*)(bp0  + kk * 32);
    s16x8 b1 = *(const s16x8*)(bp1  + kk * 32);
    acc0 = __builtin_amdgcn_mfma_f32_16x16x32_bf16(a, b0, acc0, 0, 0, 0);
    acc1 = __builtin_amdgcn_mfma_f32_16x16x32_bf16(a, b1, acc1, 0, 0, 0);
  }
#pragma unroll
  for (int r = 0; r < 4; ++r) {
    const int m = m0 + lc * 4 + r;
    out[(size_t)m * V_ + lr]      = acc0[r] + bias[lr];
    out[(size_t)m * V_ + 16 + lr] = acc1[r] + bias[16 + lr];
  }
}

// ---------------- launcher ----------------
extern "C" void kernel_launch(void* const* d_in, const int* in_sizes, int n_in,
                              void* d_out, int out_size, void* d_ws, size_t ws_size,
                              hipStream_t stream) {
  // sanity: dict-order inputs with expected element counts
  if (n_in != 7) return;
  const int exp_sz[7] = {B_ * T_ * F_, H_ * H_, H_ * F_, H_, H_, V_ * H_, V_};
  for (int i = 0; i < 7; ++i) if (in_sizes[i] != exp_sz[i]) return;

  const float* x    = (const float*)d_in[0];   // f32 (B,T,F)
  const int*   Wr4  = (const int*)d_in[1];     // int32 (H,H)
  const int*   Wi4  = (const int*)d_in[2];     // int32 (H,F)
  const float* Sres = (const float*)d_in[3];   // f32 (H)
  const float* Sin  = (const float*)d_in[4];   // f32 (H)
  const float* Wo   = (const float*)d_in[5];   // f32 (V,H)
  const float* Wob  = (const float*)d_in[6];   // f32 (V)
  float* out = (float*)d_out;
  char* ws = (char*)d_ws;

  // workspace layout (bytes)
  const size_t OFF_WRB = 0;                           //  8,388,608 (H*H bf16)
  const size_t OFF_WIB = 8388608;                     //    524,288 (H*F bf16)
  const size_t OFF_WOB = 8912896;                     //    131,072 (V*H bf16)
  const size_t OFF_OIN = 9043968;                     // 67,108,864 (int16 T*H*B)
  const size_t OFF_HS  = 76152832;                    // 67,108,864 (bf16 B*T*H)
  const size_t OFF_HB  = 143261696;                   //    262,144 (2 x B*H bf16 ping-pong)
  const size_t NEED    = 143523840;
  if (ws_size < NEED) return;

  short* WrB = (short*)(ws + OFF_WRB);
  short* WiB = (short*)(ws + OFF_WIB);
  short* WoB = (short*)(ws + OFF_WOB);
  short* Oin = (short*)(ws + OFF_OIN);
  short* HsP = (short*)(ws + OFF_HS);
  short* Hb  = (short*)(ws + OFF_HB);

  // h0 = 0 (ping buffer 0; buffer 1 fully written at t=0). bf16 zero = 0x0000.
  hipMemsetAsync(Hb, 0, B_ * H_ * 2, stream);

  pack_k<<<dim3(H_ * H_ / (4 * 256)), dim3(256), 0, stream>>>(Wr4, Wi4, Wo, WrB, WiB, WoB);
  in_gemm<<<dim3(T_, H_ / 128), dim3(256), 0, stream>>>(x, WiB, Oin);

  {
    const short* WrBc = WrB;
    const short* Oinc = Oin;
    const float* Sresc = Sres;
    const float* Sinc = Sin;
    short* Hbc = Hb;
    short* Hsc = HsP;
    void* kargs[] = {(void*)&WrBc, (void*)&Oinc, (void*)&Sresc,
                     (void*)&Sinc, (void*)&Hbc,  (void*)&Hsc};
    hipLaunchCooperativeKernel((const void*)recur_coop, dim3(64), dim3(256),
                               kargs, 0, stream);
  }

  out_gemm<<<dim3(256), dim3(256), 0, stream>>>((const unsigned short*)HsP,
                                                (const unsigned short*)WoB, Wob, out);
}

// Round 12
// 12804.083 us; speedup vs baseline: 1.4724x; 1.4724x over previous
//
#include <hip/hip_runtime.h>
#include <hip/hip_bf16.h>

typedef __attribute__((ext_vector_type(4))) int   i32x4;
typedef __attribute__((ext_vector_type(4))) float f32x4;
typedef __attribute__((ext_vector_type(4))) short s16x4;
typedef __attribute__((ext_vector_type(8))) short s16x8;

#define B_  32
#define T_  512
#define F_  128
#define H_  2048
#define V_  32
#define NBLK_ 64

static __device__ __forceinline__ int clampi16(int v) {
  v = v < -32768 ? -32768 : v;
  return v > 32767 ? 32767 : v;
}
static __device__ __forceinline__ short f2bf(float f) {
  union { __hip_bfloat16 b; short s; } u; u.b = __float2bfloat16(f); return u.s;
}

// XLA-CPU tanh under legacy fast-math: Eigen/XLA rational approximation with
// FMA-contracted Horner chains. (R10-validated bit-level grading target.)
static __device__ __forceinline__ float xla_tanh_fma(float x) {
#pragma clang fp contract(off)
  const float kClamp = 7.90531110763549805f;
  float xc = fminf(fmaxf(x, -kClamp), kClamp);
  float x2 = xc * xc;
  float a;
  a = -2.76076847742355e-16f;                          // alpha_13
  a = __builtin_fmaf(a, x2, 2.00018790482477e-13f);    // alpha_11
  a = __builtin_fmaf(a, x2, -8.60467152213735e-11f);   // alpha_9
  a = __builtin_fmaf(a, x2, 5.12229709037114e-08f);    // alpha_7
  a = __builtin_fmaf(a, x2, 1.48572235717979e-05f);    // alpha_5
  a = __builtin_fmaf(a, x2, 6.37261928875436e-04f);    // alpha_3
  a = __builtin_fmaf(a, x2, 4.89352455891786e-03f);    // alpha_1
  float num = xc * a;
  float b;
  b = 1.19825839466702e-06f;                           // beta_6
  b = __builtin_fmaf(b, x2, 1.18534705686654e-04f);    // beta_4
  b = __builtin_fmaf(b, x2, 2.26843463243900e-03f);    // beta_2
  b = __builtin_fmaf(b, x2, 4.89352518554385e-03f);    // beta_0
  float r = num / b;                                   // IEEE div
  return (fabsf(x) < 0.0004f) ? x : r;
}

// ---------------- Phase 0: pack weights to bf16 (exact: |w|<=7) ----------------
__global__ __launch_bounds__(256) void pack_k(const int* __restrict__ Wr4,
                                              const int* __restrict__ Wi4,
                                              const float* __restrict__ Wo,
                                              short* __restrict__ WrB,
                                              short* __restrict__ WiB,
                                              short* __restrict__ WoB) {
  const int idx = blockIdx.x * 256 + threadIdx.x;  // grid 4096 -> 1,048,576
  {
    i32x4 v = *(const i32x4*)(Wr4 + (size_t)idx * 4);
    s16x4 o;
#pragma unroll
    for (int r = 0; r < 4; ++r) o[r] = f2bf((float)v[r]);
    *(s16x4*)(WrB + (size_t)idx * 4) = o;
  }
  if (idx < (H_ * F_ / 4)) {
    i32x4 v = *(const i32x4*)(Wi4 + (size_t)idx * 4);
    s16x4 o;
#pragma unroll
    for (int r = 0; r < 4; ++r) o[r] = f2bf((float)v[r]);
    *(s16x4*)(WiB + (size_t)idx * 4) = o;
  }
  if (idx < (V_ * H_ / 4)) {
    f32x4 f = *(const f32x4*)(Wo + (size_t)idx * 4);
    s16x4 o;
#pragma unroll
    for (int r = 0; r < 4; ++r) o[r] = f2bf(f[r]);
    *(s16x4*)(WoB + (size_t)idx * 4) = o;
  }
}

// ---------------- Phase 1: Oin[t][j][b] = clip(u_int @ Wi^T, int16) ----------------
__global__ __launch_bounds__(256) void in_gemm(const float* __restrict__ x,
                                               const short* __restrict__ WiB,
                                               short* __restrict__ Oin) {
  const int t  = blockIdx.x;
  const int jt = blockIdx.y;
  const int tid = threadIdx.x;
  const int l = tid & 63, w = tid >> 6;
  const int mh = w & 1, q = w >> 1;
  const int lr = l & 15, lc = l >> 4;
  const int brow = mh * 16 + lr;

  s16x8 af[4];
  const float* xp = x + ((size_t)brow * T_ + t) * F_;
#pragma unroll
  for (int kk = 0; kk < 4; ++kk) {
    f32x4 f0 = *(const f32x4*)(xp + kk * 32 + lc * 8);
    f32x4 f1 = *(const f32x4*)(xp + kk * 32 + lc * 8 + 4);
    s16x8 a;
#pragma unroll
    for (int c = 0; c < 4; ++c) a[c]     = f2bf(rintf(f0[c] * 7.0f));
#pragma unroll
    for (int c = 0; c < 4; ++c) a[4 + c] = f2bf(rintf(f1[c] * 7.0f));
    af[kk] = a;
  }
#pragma unroll
  for (int s = 0; s < 4; ++s) {
    const int j = jt * 128 + q * 64 + s * 16 + lr;
    f32x4 acc = {0.f, 0.f, 0.f, 0.f};
#pragma unroll
    for (int kk = 0; kk < 4; ++kk) {
      s16x8 b = *(const s16x8*)(WiB + (size_t)j * F_ + kk * 32 + lc * 8);
      acc = __builtin_amdgcn_mfma_f32_16x16x32_bf16(af[kk], b, acc, 0, 0, 0);
    }
    short* op = Oin + ((size_t)t * H_ + j) * B_ + mh * 16 + lc * 4;
    s16x4 ov;
#pragma unroll
    for (int r = 0; r < 4; ++r) ov[r] = (short)clampi16((int)acc[r]);
    *(s16x4*)op = ov;
  }
}

// ---------------- Phase 2: persistent recurrence, custom grid barrier ----------------
// Plain launch, 64 blocks x 256 thr (<= 256 CUs -> co-resident by capacity).
// Monotonic barrier: atomicAdd + spin(cnt >= NBLK*(t+1)); release via
// __threadfence (XCD-L2 writeback), acquire via agent-scope atomic load.
// Wr fragments pinned in ~256 VGPRs via opaque asm (defeats remat; R11 showed
// VGPR=56 -> compiler had sunk the preload back into the loop).
// Numerics bit-identical to R10-validated step_k.
__global__ __launch_bounds__(256, 1) void recur_pers(const short* __restrict__ WrB,
                                                     const short* __restrict__ Oin,
                                                     const float* __restrict__ Sres,
                                                     const float* __restrict__ Sin,
                                                     short* __restrict__ Hb,
                                                     short* __restrict__ Hs,
                                                     int* __restrict__ barcnt) {
#pragma clang fp contract(off)
  const int tid = threadIdx.x;
  const int l = tid & 63, w = tid >> 6;
  const int mh = w & 1, nh = w >> 1;
  const int lr = l & 15, lc = l >> 4;
  const int jl = blockIdx.x * 32 + nh * 16 + lr;   // unit (MFMA col)
  const int b0 = mh * 16;

  const float RC49 = 1.0f / 49.0f;
  const float sres = Sres[jl] * RC49;    // fast-math: x/49 -> x*(1/49)
  const float sinl = Sin[jl]  * RC49;

  // Preload W row fragments into VGPRs and PIN them (opaque asm kills remat).
  const short* wrow = WrB + (size_t)jl * H_ + lc * 8;
  s16x8 wreg[64];
#pragma unroll
  for (int kk = 0; kk < 64; ++kk) {
    wreg[kk] = *(const s16x8*)(wrow + kk * 32);
    asm volatile("" : "+v"(wreg[kk]));
  }

  for (int t = 0; t < T_; ++t) {
    const short* hin  = Hb + (t & 1) * (B_ * H_);
    short*       hout = Hb + ((t + 1) & 1) * (B_ * H_);
    const short* hrow = hin + (size_t)(b0 + lr) * H_ + lc * 8;

    f32x4 acc0 = {0.f, 0.f, 0.f, 0.f}, acc1 = {0.f, 0.f, 0.f, 0.f};
#pragma unroll 8
    for (int kk = 0; kk < 64; kk += 2) {
      s16x8 a0 = *(const s16x8*)(hrow + kk * 32);
      s16x8 a1 = *(const s16x8*)(hrow + kk * 32 + 32);
      acc0 = __builtin_amdgcn_mfma_f32_16x16x32_bf16(a0, wreg[kk],     acc0, 0, 0, 0);
      acc1 = __builtin_amdgcn_mfma_f32_16x16x32_bf16(a1, wreg[kk + 1], acc1, 0, 0, 0);
    }

    const s16x4 oin = *(const s16x4*)(Oin + ((size_t)t * H_ + jl) * B_ + b0 + lc * 4);

#pragma unroll
    for (int r = 0; r < 4; ++r) {
      const int b = b0 + lc * 4 + r;
      const float resf = acc0[r] + acc1[r];          // exact integer in f32
      const int   res  = clampi16((int)resf);
      const float t2   = (float)oin[r] * sinl;
      const float z    = __builtin_fmaf((float)res, sres, t2);
      const float h    = xla_tanh_fma(z);
      const float hc   = fminf(fmaxf(h, -1.0f), 1.0f);
      Hs[((size_t)b * T_ + t) * H_ + jl] = f2bf(h);
      hout[(size_t)b * H_ + jl] = f2bf(rintf(hc * 7.0f));
    }

    if (t != T_ - 1) {
      __syncthreads();                 // all waves of block done (waitcnt+barrier)
      if (tid == 0) {
        __threadfence();               // release: write back this XCD's L2
        __hip_atomic_fetch_add(barcnt, 1, __ATOMIC_RELEASE, __HIP_MEMORY_SCOPE_AGENT);
        while (__hip_atomic_load(barcnt, __ATOMIC_ACQUIRE, __HIP_MEMORY_SCOPE_AGENT)
               < NBLK_ * (t + 1)) {
          __builtin_amdgcn_s_sleep(1);
        }
      }
      __syncthreads();                 // fan the acquire out to all waves
    }
  }
}

// ---------------- Phase 3: out(f32) = Hs(bf16) @ Wo(bf16)^T + bias ----------------
__global__ __launch_bounds__(256) void out_gemm(const unsigned short* __restrict__ Hs,
                                                const unsigned short* __restrict__ WoB,
                                                const float* __restrict__ bias,
                                                float* __restrict__ out) {
  const int tid = threadIdx.x;
  const int l = tid & 63, w = tid >> 6;
  const int m0 = blockIdx.x * 64 + w * 16;
  const int lr = l & 15, lc = l >> 4;

  f32x4 acc0 = {0.f, 0.f, 0.f, 0.f}, acc1 = {0.f, 0.f, 0.f, 0.f};
  const unsigned short* arow = Hs  + (size_t)(m0 + lr) * H_ + lc * 8;
  const unsigned short* bp0  = WoB + (size_t)lr * H_        + lc * 8;
  const unsigned short* bp1  = WoB + (size_t)(16 + lr) * H_ + lc * 8;
#pragma unroll 8
  for (int kk = 0; kk < 64; ++kk) {
    s16x8 a  = *(const s16x8*)(arow + kk * 32);
    s16x8 b0 = *(const s16x8*)(bp0  + kk * 32);
    s16x8 b1 = *(const s16x8*)(bp1  + kk * 32);
    acc0 = __builtin_amdgcn_mfma_f32_16x16x32_bf16(a, b0, acc0, 0, 0, 0);
    acc1 = __builtin_amdgcn_mfma_f32_16x16x32_bf16(a, b1, acc1, 0, 0, 0);
  }
#pragma unroll
  for (int r = 0; r < 4; ++r) {
    const int m = m0 + lc * 4 + r;
    out[(size_t)m * V_ + lr]      = acc0[r] + bias[lr];
    out[(size_t)m * V_ + 16 + lr] = acc1[r] + bias[16 + lr];
  }
}

// ---------------- launcher ----------------
extern "C" void kernel_launch(void* const* d_in, const int* in_sizes, int n_in,
                              void* d_out, int out_size, void* d_ws, size_t ws_size,
                              hipStream_t stream) {
  // sanity: dict-order inputs with expected element counts
  if (n_in != 7) return;
  const int exp_sz[7] = {B_ * T_ * F_, H_ * H_, H_ * F_, H_, H_, V_ * H_, V_};
  for (int i = 0; i < 7; ++i) if (in_sizes[i] != exp_sz[i]) return;

  const float* x    = (const float*)d_in[0];   // f32 (B,T,F)
  const int*   Wr4  = (const int*)d_in[1];     // int32 (H,H)
  const int*   Wi4  = (const int*)d_in[2];     // int32 (H,F)
  const float* Sres = (const float*)d_in[3];   // f32 (H)
  const float* Sin  = (const float*)d_in[4];   // f32 (H)
  const float* Wo   = (const float*)d_in[5];   // f32 (V,H)
  const float* Wob  = (const float*)d_in[6];   // f32 (V)
  float* out = (float*)d_out;
  char* ws = (char*)d_ws;

  // workspace layout (bytes)
  const size_t OFF_WRB = 0;                           //  8,388,608 (H*H bf16)
  const size_t OFF_WIB = 8388608;                     //    524,288 (H*F bf16)
  const size_t OFF_WOB = 8912896;                     //    131,072 (V*H bf16)
  const size_t OFF_OIN = 9043968;                     // 67,108,864 (int16 T*H*B)
  const size_t OFF_HS  = 76152832;                    // 67,108,864 (bf16 B*T*H)
  const size_t OFF_HB  = 143261696;                   //    262,144 (2 x B*H bf16 ping-pong)
  const size_t OFF_BAR = 143523840;                   //        256 (barrier counter)
  const size_t NEED    = 143524096;
  if (ws_size < NEED) return;

  short* WrB = (short*)(ws + OFF_WRB);
  short* WiB = (short*)(ws + OFF_WIB);
  short* WoB = (short*)(ws + OFF_WOB);
  short* Oin = (short*)(ws + OFF_OIN);
  short* HsP = (short*)(ws + OFF_HS);
  short* Hb  = (short*)(ws + OFF_HB);
  int*   Bar = (int*)(ws + OFF_BAR);

  // h0 = 0 (ping buffer 0; buffer 1 fully written at t=0); barrier counter = 0.
  hipMemsetAsync(Hb, 0, B_ * H_ * 2, stream);
  hipMemsetAsync(Bar, 0, 256, stream);

  pack_k<<<dim3(H_ * H_ / (4 * 256)), dim3(256), 0, stream>>>(Wr4, Wi4, Wo, WrB, WiB, WoB);
  in_gemm<<<dim3(T_, H_ / 128), dim3(256), 0, stream>>>(x, WiB, Oin);

  recur_pers<<<dim3(NBLK_), dim3(256), 0, stream>>>(WrB, Oin, Sres, Sin, Hb, HsP, Bar);

  out_gemm<<<dim3(256), dim3(256), 0, stream>>>((const unsigned short*)HsP,
                                                (const unsigned short*)WoB, Wob, out);
}

// Round 13
// 7695.766 us; speedup vs baseline: 2.4497x; 1.6638x over previous
//
#include <hip/hip_runtime.h>
#include <hip/hip_bf16.h>

typedef __attribute__((ext_vector_type(4))) int   i32x4;
typedef __attribute__((ext_vector_type(4))) float f32x4;
typedef __attribute__((ext_vector_type(4))) short s16x4;
typedef __attribute__((ext_vector_type(8))) short s16x8;

#define B_  32
#define T_  512
#define F_  128
#define H_  2048
#define V_  32
#define NBLK_ 64

static __device__ __forceinline__ int clampi16(int v) {
  v = v < -32768 ? -32768 : v;
  return v > 32767 ? 32767 : v;
}
static __device__ __forceinline__ short f2bf(float f) {
  union { __hip_bfloat16 b; short s; } u; u.b = __float2bfloat16(f); return u.s;
}

// XLA-CPU tanh under legacy fast-math: Eigen/XLA rational approximation with
// FMA-contracted Horner chains. (R10-validated bit-level grading target.)
static __device__ __forceinline__ float xla_tanh_fma(float x) {
#pragma clang fp contract(off)
  const float kClamp = 7.90531110763549805f;
  float xc = fminf(fmaxf(x, -kClamp), kClamp);
  float x2 = xc * xc;
  float a;
  a = -2.76076847742355e-16f;                          // alpha_13
  a = __builtin_fmaf(a, x2, 2.00018790482477e-13f);    // alpha_11
  a = __builtin_fmaf(a, x2, -8.60467152213735e-11f);   // alpha_9
  a = __builtin_fmaf(a, x2, 5.12229709037114e-08f);    // alpha_7
  a = __builtin_fmaf(a, x2, 1.48572235717979e-05f);    // alpha_5
  a = __builtin_fmaf(a, x2, 6.37261928875436e-04f);    // alpha_3
  a = __builtin_fmaf(a, x2, 4.89352455891786e-03f);    // alpha_1
  float num = xc * a;
  float b;
  b = 1.19825839466702e-06f;                           // beta_6
  b = __builtin_fmaf(b, x2, 1.18534705686654e-04f);    // beta_4
  b = __builtin_fmaf(b, x2, 2.26843463243900e-03f);    // beta_2
  b = __builtin_fmaf(b, x2, 4.89352518554385e-03f);    // beta_0
  float r = num / b;                                   // IEEE div
  return (fabsf(x) < 0.0004f) ? x : r;
}

// ---------------- Phase 0: pack weights to bf16 (exact: |w|<=7) ----------------
__global__ __launch_bounds__(256) void pack_k(const int* __restrict__ Wr4,
                                              const int* __restrict__ Wi4,
                                              const float* __restrict__ Wo,
                                              short* __restrict__ WrB,
                                              short* __restrict__ WiB,
                                              short* __restrict__ WoB) {
  const int idx = blockIdx.x * 256 + threadIdx.x;  // grid 4096 -> 1,048,576
  {
    i32x4 v = *(const i32x4*)(Wr4 + (size_t)idx * 4);
    s16x4 o;
#pragma unroll
    for (int r = 0; r < 4; ++r) o[r] = f2bf((float)v[r]);
    *(s16x4*)(WrB + (size_t)idx * 4) = o;
  }
  if (idx < (H_ * F_ / 4)) {
    i32x4 v = *(const i32x4*)(Wi4 + (size_t)idx * 4);
    s16x4 o;
#pragma unroll
    for (int r = 0; r < 4; ++r) o[r] = f2bf((float)v[r]);
    *(s16x4*)(WiB + (size_t)idx * 4) = o;
  }
  if (idx < (V_ * H_ / 4)) {
    f32x4 f = *(const f32x4*)(Wo + (size_t)idx * 4);
    s16x4 o;
#pragma unroll
    for (int r = 0; r < 4; ++r) o[r] = f2bf(f[r]);
    *(s16x4*)(WoB + (size_t)idx * 4) = o;
  }
}

// ---------------- Phase 1: Oin[t][j][b] = clip(u_int @ Wi^T, int16) ----------------
__global__ __launch_bounds__(256) void in_gemm(const float* __restrict__ x,
                                               const short* __restrict__ WiB,
                                               short* __restrict__ Oin) {
  const int t  = blockIdx.x;
  const int jt = blockIdx.y;
  const int tid = threadIdx.x;
  const int l = tid & 63, w = tid >> 6;
  const int mh = w & 1, q = w >> 1;
  const int lr = l & 15, lc = l >> 4;
  const int brow = mh * 16 + lr;

  s16x8 af[4];
  const float* xp = x + ((size_t)brow * T_ + t) * F_;
#pragma unroll
  for (int kk = 0; kk < 4; ++kk) {
    f32x4 f0 = *(const f32x4*)(xp + kk * 32 + lc * 8);
    f32x4 f1 = *(const f32x4*)(xp + kk * 32 + lc * 8 + 4);
    s16x8 a;
#pragma unroll
    for (int c = 0; c < 4; ++c) a[c]     = f2bf(rintf(f0[c] * 7.0f));
#pragma unroll
    for (int c = 0; c < 4; ++c) a[4 + c] = f2bf(rintf(f1[c] * 7.0f));
    af[kk] = a;
  }
#pragma unroll
  for (int s = 0; s < 4; ++s) {
    const int j = jt * 128 + q * 64 + s * 16 + lr;
    f32x4 acc = {0.f, 0.f, 0.f, 0.f};
#pragma unroll
    for (int kk = 0; kk < 4; ++kk) {
      s16x8 b = *(const s16x8*)(WiB + (size_t)j * F_ + kk * 32 + lc * 8);
      acc = __builtin_amdgcn_mfma_f32_16x16x32_bf16(af[kk], b, acc, 0, 0, 0);
    }
    short* op = Oin + ((size_t)t * H_ + j) * B_ + mh * 16 + lc * 4;
    s16x4 ov;
#pragma unroll
    for (int r = 0; r < 4; ++r) ov[r] = (short)clampi16((int)acc[r]);
    *(s16x4*)op = ov;
  }
}

// ---------------- Phase 2: persistent recurrence, fixed grid barrier ----------------
// R13 fixes vs R12 (concept unchanged, numerics bit-identical):
//  (a) MFMA loop FULLY unrolled -> wreg[] compile-time indexed -> truly lives
//      in ~256 VGPRs (R12's unroll-8 made kk runtime -> scratch, VGPR=40).
//  (b) Barrier: RELEASE atomicAdd once (own writeback), RELAXED polls (no
//      buffer_inv per poll!), single acquire fence on exit. R12 did an
//      ACQUIRE load per poll -> per-poll XCD cache invalidation storm.
__global__ __launch_bounds__(256, 1) void recur_pers(const short* __restrict__ WrB,
                                                     const short* __restrict__ Oin,
                                                     const float* __restrict__ Sres,
                                                     const float* __restrict__ Sin,
                                                     short* __restrict__ Hb,
                                                     short* __restrict__ Hs,
                                                     int* __restrict__ barcnt) {
#pragma clang fp contract(off)
  const int tid = threadIdx.x;
  const int l = tid & 63, w = tid >> 6;
  const int mh = w & 1, nh = w >> 1;
  const int lr = l & 15, lc = l >> 4;
  const int jl = blockIdx.x * 32 + nh * 16 + lr;   // unit (MFMA col)
  const int b0 = mh * 16;

  const float RC49 = 1.0f / 49.0f;
  const float sres = Sres[jl] * RC49;    // fast-math: x/49 -> x*(1/49)
  const float sinl = Sin[jl]  * RC49;

  // Preload W row fragments into VGPRs and pin (asm defeats remat; full
  // unroll below keeps every index compile-time).
  const short* wrow = WrB + (size_t)jl * H_ + lc * 8;
  s16x8 wreg[64];
#pragma unroll
  for (int kk = 0; kk < 64; ++kk) {
    wreg[kk] = *(const s16x8*)(wrow + kk * 32);
    asm volatile("" : "+v"(wreg[kk]));
  }

  for (int t = 0; t < T_; ++t) {
    const short* hin  = Hb + (t & 1) * (B_ * H_);
    short*       hout = Hb + ((t + 1) & 1) * (B_ * H_);
    const short* hrow = hin + (size_t)(b0 + lr) * H_ + lc * 8;

    const s16x4 oin = *(const s16x4*)(Oin + ((size_t)t * H_ + jl) * B_ + b0 + lc * 4);

    f32x4 acc0 = {0.f, 0.f, 0.f, 0.f}, acc1 = {0.f, 0.f, 0.f, 0.f};
#pragma unroll
    for (int kk = 0; kk < 64; kk += 2) {             // FULL unroll: kk constant
      s16x8 a0 = *(const s16x8*)(hrow + kk * 32);
      s16x8 a1 = *(const s16x8*)(hrow + kk * 32 + 32);
      acc0 = __builtin_amdgcn_mfma_f32_16x16x32_bf16(a0, wreg[kk],     acc0, 0, 0, 0);
      acc1 = __builtin_amdgcn_mfma_f32_16x16x32_bf16(a1, wreg[kk + 1], acc1, 0, 0, 0);
    }

#pragma unroll
    for (int r = 0; r < 4; ++r) {
      const int b = b0 + lc * 4 + r;
      const float resf = acc0[r] + acc1[r];          // exact integer in f32
      const int   res  = clampi16((int)resf);
      const float t2   = (float)oin[r] * sinl;
      const float z    = __builtin_fmaf((float)res, sres, t2);
      const float h    = xla_tanh_fma(z);
      const float hc   = fminf(fmaxf(h, -1.0f), 1.0f);
      Hs[((size_t)b * T_ + t) * H_ + jl] = f2bf(h);
      hout[(size_t)b * H_ + jl] = f2bf(rintf(hc * 7.0f));
    }

    if (t != T_ - 1) {
      __syncthreads();   // block's stores complete (s_waitcnt) before arrival
      if (tid == 0) {
        // arrival: RELEASE add (performs the XCD-L2 writeback once)
        __hip_atomic_fetch_add(barcnt, 1, __ATOMIC_RELEASE, __HIP_MEMORY_SCOPE_AGENT);
        // spin: RELAXED loads -- no cache ops per poll
        while (__hip_atomic_load(barcnt, __ATOMIC_RELAXED, __HIP_MEMORY_SCOPE_AGENT)
               < NBLK_ * (t + 1)) {
          __builtin_amdgcn_s_sleep(2);
        }
        // single acquire: invalidate stale lines once, then proceed
        __builtin_amdgcn_fence(__ATOMIC_ACQUIRE, "agent");
      }
      __syncthreads();   // fan out
    }
  }
}

// ---------------- Phase 3: out(f32) = Hs(bf16) @ Wo(bf16)^T + bias ----------------
__global__ __launch_bounds__(256) void out_gemm(const unsigned short* __restrict__ Hs,
                                                const unsigned short* __restrict__ WoB,
                                                const float* __restrict__ bias,
                                                float* __restrict__ out) {
  const int tid = threadIdx.x;
  const int l = tid & 63, w = tid >> 6;
  const int m0 = blockIdx.x * 64 + w * 16;
  const int lr = l & 15, lc = l >> 4;

  f32x4 acc0 = {0.f, 0.f, 0.f, 0.f}, acc1 = {0.f, 0.f, 0.f, 0.f};
  const unsigned short* arow = Hs  + (size_t)(m0 + lr) * H_ + lc * 8;
  const unsigned short* bp0  = WoB + (size_t)lr * H_        + lc * 8;
  const unsigned short* bp1  = WoB + (size_t)(16 + lr) * H_ + lc * 8;
#pragma unroll 8
  for (int kk = 0; kk < 64; ++kk) {
    s16x8 a  = *(const s16x8*)(arow + kk * 32);
    s16x8 b0 = *(const s16x8*)(bp0  + kk * 32);
    s16x8 b1 = *(const s16x8*)(bp1  + kk * 32);
    acc0 = __builtin_amdgcn_mfma_f32_16x16x32_bf16(a, b0, acc0, 0, 0, 0);
    acc1 = __builtin_amdgcn_mfma_f32_16x16x32_bf16(a, b1, acc1, 0, 0, 0);
  }
#pragma unroll
  for (int r = 0; r < 4; ++r) {
    const int m = m0 + lc * 4 + r;
    out[(size_t)m * V_ + lr]      = acc0[r] + bias[lr];
    out[(size_t)m * V_ + 16 + lr] = acc1[r] + bias[16 + lr];
  }
}

// ---------------- launcher ----------------
extern "C" void kernel_launch(void* const* d_in, const int* in_sizes, int n_in,
                              void* d_out, int out_size, void* d_ws, size_t ws_size,
                              hipStream_t stream) {
  // sanity: dict-order inputs with expected element counts
  if (n_in != 7) return;
  const int exp_sz[7] = {B_ * T_ * F_, H_ * H_, H_ * F_, H_, H_, V_ * H_, V_};
  for (int i = 0; i < 7; ++i) if (in_sizes[i] != exp_sz[i]) return;

  const float* x    = (const float*)d_in[0];   // f32 (B,T,F)
  const int*   Wr4  = (const int*)d_in[1];     // int32 (H,H)
  const int*   Wi4  = (const int*)d_in[2];     // int32 (H,F)
  const float* Sres = (const float*)d_in[3];   // f32 (H)
  const float* Sin  = (const float*)d_in[4];   // f32 (H)
  const float* Wo   = (const float*)d_in[5];   // f32 (V,H)
  const float* Wob  = (const float*)d_in[6];   // f32 (V)
  float* out = (float*)d_out;
  char* ws = (char*)d_ws;

  // workspace layout (bytes)
  const size_t OFF_WRB = 0;                           //  8,388,608 (H*H bf16)
  const size_t OFF_WIB = 8388608;                     //    524,288 (H*F bf16)
  const size_t OFF_WOB = 8912896;                     //    131,072 (V*H bf16)
  const size_t OFF_OIN = 9043968;                     // 67,108,864 (int16 T*H*B)
  const size_t OFF_HS  = 76152832;                    // 67,108,864 (bf16 B*T*H)
  const size_t OFF_HB  = 143261696;                   //    262,144 (2 x B*H bf16 ping-pong)
  const size_t OFF_BAR = 143523840;                   //        256 (barrier counter)
  const size_t NEED    = 143524096;
  if (ws_size < NEED) return;

  short* WrB = (short*)(ws + OFF_WRB);
  short* WiB = (short*)(ws + OFF_WIB);
  short* WoB = (short*)(ws + OFF_WOB);
  short* Oin = (short*)(ws + OFF_OIN);
  short* HsP = (short*)(ws + OFF_HS);
  short* Hb  = (short*)(ws + OFF_HB);
  int*   Bar = (int*)(ws + OFF_BAR);

  // h0 = 0 (ping buffer 0; buffer 1 fully written at t=0); barrier counter = 0.
  hipMemsetAsync(Hb, 0, B_ * H_ * 2, stream);
  hipMemsetAsync(Bar, 0, 256, stream);

  pack_k<<<dim3(H_ * H_ / (4 * 256)), dim3(256), 0, stream>>>(Wr4, Wi4, Wo, WrB, WiB, WoB);
  in_gemm<<<dim3(T_, H_ / 128), dim3(256), 0, stream>>>(x, WiB, Oin);

  recur_pers<<<dim3(NBLK_), dim3(256), 0, stream>>>(WrB, Oin, Sres, Sin, Hb, HsP, Bar);

  out_gemm<<<dim3(256), dim3(256), 0, stream>>>((const unsigned short*)HsP,
                                                (const unsigned short*)WoB, Wob, out);
}